// Round 2
// baseline (444.198 us; speedup 1.0000x reference)
//
#include <hip/hip_runtime.h>
#include <math.h>

// Problem constants (match reference setup_inputs)
#define NB 8
#define NC 256
#define NF 16384
#define NSTEPS 20

typedef unsigned short u16;
typedef unsigned int u32;
typedef __bf16 bf16x8 __attribute__((ext_vector_type(8)));
typedef float f32x4 __attribute__((ext_vector_type(4)));

__device__ __forceinline__ u16 f2bf(float f) {
    u32 u = __float_as_uint(f);
    u += 0x7fffu + ((u >> 16) & 1u);   // round-to-nearest-even
    return (u16)(u >> 16);
}

// ---------------------------------------------------------------------------
// Kernel 1: W_conv [1024,256] fp32 -> Wt [256 n][1024 k] bf16 (transposed)
// ---------------------------------------------------------------------------
__global__ void prep_w_kernel(const float* __restrict__ Wc, u16* __restrict__ Wt) {
    int i = blockIdx.x * 256 + threadIdx.x;   // over 256*1024
    int n = i >> 10, k = i & 1023;
    Wt[i] = f2bf(Wc[k * 256 + n]);
}

// ---------------------------------------------------------------------------
// Kernel 2: transpose x [B,C,F] fp32 -> featsT [B,F,C] bf16, plus partial
// dot(feats, W_mlp) per face per 64-channel tile (for init_scores).
// ---------------------------------------------------------------------------
__global__ __launch_bounds__(256) void transpose_kernel(
    const float* __restrict__ x, u16* __restrict__ featsT,
    const float* __restrict__ W_mlp, float* __restrict__ partS) {
    __shared__ float tile[64][69];   // odd pad -> 2-way LDS banks on col reads (free)
    __shared__ float psum[64][4];
    int ft = blockIdx.x, ct = blockIdx.y, b = blockIdx.z;
    int t = threadIdx.x;
    int r = t >> 2, cg = t & 3;

    const float* xp = x + ((size_t)(b * 256 + ct * 64 + r)) * NF + ft * 64 + cg * 16;
    float4 v0 = *(const float4*)(xp + 0);
    float4 v1 = *(const float4*)(xp + 4);
    float4 v2 = *(const float4*)(xp + 8);
    float4 v3 = *(const float4*)(xp + 12);
    float* tr = &tile[r][cg * 16];
    tr[0] = v0.x; tr[1] = v0.y; tr[2]  = v0.z; tr[3]  = v0.w;
    tr[4] = v1.x; tr[5] = v1.y; tr[6]  = v1.z; tr[7]  = v1.w;
    tr[8] = v2.x; tr[9] = v2.y; tr[10] = v2.z; tr[11] = v2.w;
    tr[12] = v3.x; tr[13] = v3.y; tr[14] = v3.z; tr[15] = v3.w;
    __syncthreads();

    int fl = t >> 2;          // face local 0..63
    int c0 = cg * 16;         // channel sub-range
    float part = 0.f;
    u16 tmp[16];
#pragma unroll
    for (int j = 0; j < 16; ++j) {
        float v = tile[c0 + j][fl];
        part += v * W_mlp[ct * 64 + c0 + j];
        tmp[j] = f2bf(v);
    }
    u16* dst = featsT + ((size_t)(b * NF + ft * 64 + fl)) * 256 + ct * 64 + c0;
    u32 u[8];
#pragma unroll
    for (int j = 0; j < 8; ++j) u[j] = (u32)tmp[2 * j] | ((u32)tmp[2 * j + 1] << 16);
    uint4 p0; p0.x = u[0]; p0.y = u[1]; p0.z = u[2]; p0.w = u[3];
    uint4 p1; p1.x = u[4]; p1.y = u[5]; p1.z = u[6]; p1.w = u[7];
    *(uint4*)dst = p0;
    *(uint4*)(dst + 8) = p1;

    psum[fl][cg] = part;
    __syncthreads();
    if (t < 64) {
        float s = psum[t][0] + psum[t][1] + psum[t][2] + psum[t][3];
        partS[((size_t)(b * NF + ft * 64 + t)) * 4 + ct] = s;
    }
}

// ---------------------------------------------------------------------------
// Kernel 3: init_scores = sigmoid(sum of 4 partials + b_mlp) -> d_out scores
// ---------------------------------------------------------------------------
__global__ void init_scores_kernel(const float* __restrict__ partS,
                                   const float* __restrict__ b_mlp,
                                   float* __restrict__ sc) {
    int i = blockIdx.x * 256 + threadIdx.x;   // over B*F
    float s = partS[i * 4] + partS[i * 4 + 1] + partS[i * 4 + 2] + partS[i * 4 + 3] + b_mlp[0];
    sc[i] = 1.f / (1.f + expf(-s));
}

// ---------------------------------------------------------------------------
// Kernel 4: gathered GEMM  h = [feat|feat[adj0..2]] @ W_conv + b_conv,
// InstanceNorm over C in-epilogue, store h_norm to d_out, pred = sigmoid(h@Wmlp).
// Block: 128 faces x 256 channels (full N), 512 threads = 8 waves (2x4 of 64x64).
// __launch_bounds__(512,4): cap unified VGPR+AGPR at 128 -> 2 blocks/CU.
// Epilogue red/mstd alias the A/B LDS (51.2 KB total) so LDS never limits.
// ---------------------------------------------------------------------------
__global__ __launch_bounds__(512, 4) void conv_gemm_kernel(
    const u16* __restrict__ featsT, const u16* __restrict__ Wt,
    const float* __restrict__ b_conv, const float* __restrict__ W_mlp,
    const float* __restrict__ b_mlp, const int* __restrict__ adj,
    float* __restrict__ out_feat, float* __restrict__ pred) {
    __shared__ __align__(16) u16 AB[128 * 64 + 256 * 64];  // A: 16KB, B: 32KB
    __shared__ int srcIdx[128 * 4];
    u16* Albs = AB;
    u16* Blbs = AB + 128 * 64;
    float* red = (float*)AB;          // epilogue alias: 128*4*2 floats
    float* mstd = (float*)AB + 1024;  // epilogue alias: 128*2 floats

    int bx = blockIdx.x;
    int b = bx >> 7;
    int f0 = (bx & 127) << 7;
    int tid = threadIdx.x;
    int w = tid >> 6, lane = tid & 63;
    int wm = w >> 2, wn = w & 3;
    const int c16 = lane & 15, q4 = lane >> 4;

    if (tid < 128) {
        int f = f0 + tid;
        const int* ap = adj + ((size_t)(b * NF + f)) * 3;
        srcIdx[tid * 4 + 0] = f;
        srcIdx[tid * 4 + 1] = ap[0];
        srcIdx[tid * 4 + 2] = ap[1];
        srcIdx[tid * 4 + 3] = ap[2];
    }
    f32x4 acc[4][4] = {};
    const size_t meshBase = (size_t)b * NF * 256;
    __syncthreads();

    for (int kk = 0; kk < 16; ++kk) {
        int slot = kk >> 2;            // 0=self, 1..3=adj
        int ch0 = (kk & 3) << 6;       // channel offset within slot
        // --- stage A (gathered rows) via global_load_lds, 16B/lane ---
#pragma unroll
        for (int p = 0; p < 2; ++p) {
            int rrow = ((w * 2 + p) << 3) + (lane >> 3);
            int c8 = lane & 7;
            int src = srcIdx[rrow * 4 + slot];
            const u16* gp = featsT + meshBase + (size_t)src * 256 + ch0 + ((c8 ^ (rrow & 7)) << 3);
            __builtin_amdgcn_global_load_lds((const __attribute__((address_space(1))) void*)gp,
                                             (__attribute__((address_space(3))) void*)&Albs[(w * 2 + p) * 512],
                                             16, 0, 0);
        }
        // --- stage B (weights) ---
#pragma unroll
        for (int p = 0; p < 4; ++p) {
            int n = ((w * 4 + p) << 3) + (lane >> 3);
            int c8 = lane & 7;
            const u16* gp = Wt + n * 1024 + (kk << 6) + ((c8 ^ (n & 7)) << 3);
            __builtin_amdgcn_global_load_lds((const __attribute__((address_space(1))) void*)gp,
                                             (__attribute__((address_space(3))) void*)&Blbs[(w * 4 + p) * 512],
                                             16, 0, 0);
        }
        __syncthreads();
        // --- compute: 2 k-halves x 4x4 MFMAs ---
#pragma unroll
        for (int kh = 0; kh < 2; ++kh) {
            int k8 = (kh << 2) + q4;
            bf16x8 af[4], bfr[4];
#pragma unroll
            for (int mi = 0; mi < 4; ++mi) {
                int m = (wm << 6) + (mi << 4) + c16;
                af[mi] = *(const bf16x8*)&Albs[(m << 6) + ((k8 ^ (m & 7)) << 3)];
            }
#pragma unroll
            for (int ni = 0; ni < 4; ++ni) {
                int n = (wn << 6) + (ni << 4) + c16;
                bfr[ni] = *(const bf16x8*)&Blbs[(n << 6) + ((k8 ^ (n & 7)) << 3)];
            }
#pragma unroll
            for (int mi = 0; mi < 4; ++mi)
#pragma unroll
                for (int ni = 0; ni < 4; ++ni)
                    acc[mi][ni] = __builtin_amdgcn_mfma_f32_16x16x32_bf16(af[mi], bfr[ni], acc[mi][ni], 0, 0, 0);
        }
        __syncthreads();
    }

    // ---------------- epilogue: bias + InstanceNorm + store + pred ----------
    // (red/mstd alias the A/B LDS; safe after the final loop barrier)
    float bcv[4], wml[4];
#pragma unroll
    for (int ni = 0; ni < 4; ++ni) {
        int col = (wn << 6) + (ni << 4) + c16;
        bcv[ni] = b_conv[col];
        wml[ni] = W_mlp[col];
    }
    float s[4][4], q2[4][4];
#pragma unroll
    for (int mi = 0; mi < 4; ++mi)
#pragma unroll
        for (int r = 0; r < 4; ++r) {
            float ss = 0.f, qq = 0.f;
#pragma unroll
            for (int ni = 0; ni < 4; ++ni) {
                float v = acc[mi][ni][r] + bcv[ni];
                acc[mi][ni][r] = v;
                ss += v; qq += v * v;
            }
            s[mi][r] = ss; q2[mi][r] = qq;
        }
#pragma unroll
    for (int msk = 1; msk < 16; msk <<= 1)
#pragma unroll
        for (int mi = 0; mi < 4; ++mi)
#pragma unroll
            for (int r = 0; r < 4; ++r) {
                s[mi][r] += __shfl_xor(s[mi][r], msk);
                q2[mi][r] += __shfl_xor(q2[mi][r], msk);
            }
    if (c16 == 0) {
#pragma unroll
        for (int mi = 0; mi < 4; ++mi)
#pragma unroll
            for (int r = 0; r < 4; ++r) {
                int row = (wm << 6) + (mi << 4) + (q4 << 2) + r;
                red[(row * 4 + wn) * 2 + 0] = s[mi][r];
                red[(row * 4 + wn) * 2 + 1] = q2[mi][r];
            }
    }
    __syncthreads();
    if (tid < 128) {
        float ss = red[tid * 8 + 0] + red[tid * 8 + 2] + red[tid * 8 + 4] + red[tid * 8 + 6];
        float qq = red[tid * 8 + 1] + red[tid * 8 + 3] + red[tid * 8 + 5] + red[tid * 8 + 7];
        float mean = ss * (1.f / 256.f);
        float var = qq * (1.f / 256.f) - mean * mean;
        mstd[tid * 2 + 0] = mean;
        mstd[tid * 2 + 1] = rsqrtf(var + 1e-5f);
    }
    __syncthreads();
    float ps[4][4];
#pragma unroll
    for (int mi = 0; mi < 4; ++mi)
#pragma unroll
        for (int r = 0; r < 4; ++r) {
            int row = (wm << 6) + (mi << 4) + (q4 << 2) + r;
            float mean = mstd[row * 2], rstd = mstd[row * 2 + 1];
            float* op = out_feat + meshBase + (size_t)(f0 + row) * 256 + (wn << 6) + c16;
            float pp = 0.f;
#pragma unroll
            for (int ni = 0; ni < 4; ++ni) {
                float hn = (acc[mi][ni][r] - mean) * rstd;
                op[ni << 4] = hn;
                pp += hn * wml[ni];
            }
            ps[mi][r] = pp;
        }
#pragma unroll
    for (int msk = 1; msk < 16; msk <<= 1)
#pragma unroll
        for (int mi = 0; mi < 4; ++mi)
#pragma unroll
            for (int r = 0; r < 4; ++r)
                ps[mi][r] += __shfl_xor(ps[mi][r], msk);
    __syncthreads();
    if (c16 == 0) {
#pragma unroll
        for (int mi = 0; mi < 4; ++mi)
#pragma unroll
            for (int r = 0; r < 4; ++r) {
                int row = (wm << 6) + (mi << 4) + (q4 << 2) + r;
                red[row * 4 + wn] = ps[mi][r];
            }
    }
    __syncthreads();
    if (tid < 128) {
        float t = red[tid * 4] + red[tid * 4 + 1] + red[tid * 4 + 2] + red[tid * 4 + 3] + b_mlp[0];
        pred[b * NF + f0 + tid] = 1.f / (1.f + expf(-t));
    }
}

// ---------------------------------------------------------------------------
// Kernel 5: BFS flood fill — queue-based frontier, one block per mesh.
// Work per step ~ |frontier| (total 16K face-visits/mesh) instead of dense
// scans of all 16K bit-slots every step.
// ---------------------------------------------------------------------------
__global__ __launch_bounds__(1024) void bfs_kernel(
    const int* __restrict__ adj, const int* __restrict__ anchors,
    const float* __restrict__ pred, float* __restrict__ sc,
    u32* __restrict__ doneOut, int* __restrict__ qbuf) {
    __shared__ u32 done[512], seen[512];
    __shared__ int cntCur, cntNext;
    int b = blockIdx.x, tid = threadIdx.x;
    if (tid < 512) { done[tid] = 0u; seen[tid] = 0u; }
    if (tid == 0) { cntCur = 1; cntNext = 0; }
    int* q0 = qbuf + (size_t)b * 2 * NF;
    int* q1 = q0 + NF;
    const int* adjb = adj + (size_t)b * NF * 3;
    const float* pb = pred + b * NF;
    float* scb = sc + b * NF;
    __syncthreads();
    if (tid == 0) {
        int a = anchors[b];
        done[a >> 5] |= 1u << (a & 31);   // reference: done0 includes the anchor
        seen[a >> 5] |= 1u << (a & 31);
        q0[0] = a;
    }
    __syncthreads();
    int* qc = q0;
    int* qn = q1;
    for (int step = 0; step < NSTEPS; ++step) {
        int n = cntCur;
        for (int i = tid; i < n; i += 1024) {
            int f = qc[i];
            int a0 = adjb[f * 3 + 0], a1 = adjb[f * 3 + 1], a2 = adjb[f * 3 + 2];
            bool d0 = (done[a0 >> 5] >> (a0 & 31)) & 1u;
            bool d1 = (done[a1 >> 5] >> (a1 & 31)) & 1u;
            bool d2 = (done[a2 >> 5] >> (a2 & 31)) & 1u;
            float nb = -1.f;
            if (d0) nb = fmaxf(nb, scb[a0]);
            if (d1) nb = fmaxf(nb, scb[a1]);
            if (d2) nb = fmaxf(nb, scb[a2]);
            if (!(d0 | d1 | d2)) nb = 1.f;
            scb[f] = fminf(fmaxf(pb[f], scb[f]), nb);
            // enqueue out-neighbors not yet seen (seen = done ∪ ever-queued)
            u32 m0 = 1u << (a0 & 31);
            if (!(atomicOr(&seen[a0 >> 5], m0) & m0)) qn[atomicAdd(&cntNext, 1)] = a0;
            u32 m1 = 1u << (a1 & 31);
            if (!(atomicOr(&seen[a1 >> 5], m1) & m1)) qn[atomicAdd(&cntNext, 1)] = a1;
            u32 m2 = 1u << (a2 & 31);
            if (!(atomicOr(&seen[a2 >> 5], m2) & m2)) qn[atomicAdd(&cntNext, 1)] = a2;
        }
        __syncthreads();
        // current level now finalized -> mark done (next level sees them)
        for (int i = tid; i < n; i += 1024) {
            int f = qc[i];
            atomicOr(&done[f >> 5], 1u << (f & 31));
        }
        if (tid == 0) { cntCur = cntNext; cntNext = 0; }
        __syncthreads();
        int* t = qc; qc = qn; qn = t;
    }
    if (tid < 512) doneOut[b * 512 + tid] = done[tid];
}

// ---------------------------------------------------------------------------
// Kernel 6: faces never visited keep original (fp32) features.
// ---------------------------------------------------------------------------
__global__ void fixup_kernel(const float* __restrict__ x, const u32* __restrict__ doneBits,
                             float* __restrict__ out_feat) {
    int b = blockIdx.y;
    int f = (blockIdx.x << 8) + threadIdx.x;
    if (!((doneBits[b * 512 + (f >> 5)] >> (f & 31)) & 1u)) {
        float* op = out_feat + ((size_t)(b * NF + f)) * 256;
        const float* xp = x + (size_t)b * 256 * NF + f;
        for (int cc = 0; cc < 256; ++cc) op[cc] = xp[(size_t)cc * NF];
    }
}

// ---------------------------------------------------------------------------
extern "C" void kernel_launch(void* const* d_in, const int* in_sizes, int n_in,
                              void* d_out, int out_size, void* d_ws, size_t ws_size,
                              hipStream_t stream) {
    const float* x = (const float*)d_in[0];
    const int* adj = (const int*)d_in[1];
    const int* anchors = (const int*)d_in[2];
    const float* W_conv = (const float*)d_in[3];
    const float* b_conv = (const float*)d_in[4];
    const float* W_mlp = (const float*)d_in[5];
    const float* b_mlp = (const float*)d_in[6];

    float* out_feat = (float*)d_out;
    float* out_sc = out_feat + (size_t)NB * NF * 256;

    char* wsp = (char*)d_ws;
    u16* featsT = (u16*)wsp;  wsp += (size_t)NB * NF * 256 * 2;     // 67 MB
    u16* Wt = (u16*)wsp;      wsp += (size_t)256 * 1024 * 2;        // 512 KB
    float* partS = (float*)wsp; wsp += (size_t)NB * NF * 4 * 4;     // 2 MB
    float* pred = (float*)wsp;  wsp += (size_t)NB * NF * 4;         // 512 KB
    u32* doneBits = (u32*)wsp;  wsp += (size_t)NB * 512 * 4;        // 16 KB
    int* qbuf = (int*)wsp;      wsp += (size_t)NB * 2 * NF * 4;     // 1 MB

    prep_w_kernel<<<1024, 256, 0, stream>>>(W_conv, Wt);
    transpose_kernel<<<dim3(256, 4, NB), 256, 0, stream>>>(x, featsT, W_mlp, partS);
    init_scores_kernel<<<512, 256, 0, stream>>>(partS, b_mlp, out_sc);
    conv_gemm_kernel<<<1024, 512, 0, stream>>>(featsT, Wt, b_conv, W_mlp, b_mlp, adj, out_feat, pred);
    bfs_kernel<<<NB, 1024, 0, stream>>>(adj, anchors, pred, out_sc, doneBits, qbuf);
    fixup_kernel<<<dim3(64, NB), 256, 0, stream>>>(x, doneBits, out_feat);
}

// Round 3
// 413.953 us; speedup vs baseline: 1.0731x; 1.0731x over previous
//
#include <hip/hip_runtime.h>
#include <math.h>

// Problem constants (match reference setup_inputs)
#define NB 8
#define NC 256
#define NF 16384
#define NSTEPS 20

typedef unsigned short u16;
typedef unsigned int u32;
typedef __bf16 bf16x8 __attribute__((ext_vector_type(8)));
typedef float f32x4 __attribute__((ext_vector_type(4)));

__device__ __forceinline__ u16 f2bf(float f) {
    u32 u = __float_as_uint(f);
    u += 0x7fffu + ((u >> 16) & 1u);   // round-to-nearest-even
    return (u16)(u >> 16);
}

// ---------------------------------------------------------------------------
// Kernel 1: W_conv [1024,256] fp32 -> Wt [256 n][1024 k] bf16 (transposed)
// ---------------------------------------------------------------------------
__global__ void prep_w_kernel(const float* __restrict__ Wc, u16* __restrict__ Wt) {
    int i = blockIdx.x * 256 + threadIdx.x;   // over 256*1024
    int n = i >> 10, k = i & 1023;
    Wt[i] = f2bf(Wc[k * 256 + n]);
}

// ---------------------------------------------------------------------------
// Kernel 2: transpose x [B,C,F] fp32 -> featsT [B,F,C] bf16, plus partial
// dot(feats, W_mlp) per face per 64-channel tile (for init_scores).
// ---------------------------------------------------------------------------
__global__ __launch_bounds__(256) void transpose_kernel(
    const float* __restrict__ x, u16* __restrict__ featsT,
    const float* __restrict__ W_mlp, float* __restrict__ partS) {
    __shared__ float tile[64][69];   // odd pad -> 2-way LDS banks on col reads (free)
    __shared__ float psum[64][4];
    int ft = blockIdx.x, ct = blockIdx.y, b = blockIdx.z;
    int t = threadIdx.x;
    int r = t >> 2, cg = t & 3;

    const float* xp = x + ((size_t)(b * 256 + ct * 64 + r)) * NF + ft * 64 + cg * 16;
    float4 v0 = *(const float4*)(xp + 0);
    float4 v1 = *(const float4*)(xp + 4);
    float4 v2 = *(const float4*)(xp + 8);
    float4 v3 = *(const float4*)(xp + 12);
    float* tr = &tile[r][cg * 16];
    tr[0] = v0.x; tr[1] = v0.y; tr[2]  = v0.z; tr[3]  = v0.w;
    tr[4] = v1.x; tr[5] = v1.y; tr[6]  = v1.z; tr[7]  = v1.w;
    tr[8] = v2.x; tr[9] = v2.y; tr[10] = v2.z; tr[11] = v2.w;
    tr[12] = v3.x; tr[13] = v3.y; tr[14] = v3.z; tr[15] = v3.w;
    __syncthreads();

    int fl = t >> 2;          // face local 0..63
    int c0 = cg * 16;         // channel sub-range
    float part = 0.f;
    u16 tmp[16];
#pragma unroll
    for (int j = 0; j < 16; ++j) {
        float v = tile[c0 + j][fl];
        part += v * W_mlp[ct * 64 + c0 + j];
        tmp[j] = f2bf(v);
    }
    u16* dst = featsT + ((size_t)(b * NF + ft * 64 + fl)) * 256 + ct * 64 + c0;
    u32 u[8];
#pragma unroll
    for (int j = 0; j < 8; ++j) u[j] = (u32)tmp[2 * j] | ((u32)tmp[2 * j + 1] << 16);
    uint4 p0; p0.x = u[0]; p0.y = u[1]; p0.z = u[2]; p0.w = u[3];
    uint4 p1; p1.x = u[4]; p1.y = u[5]; p1.z = u[6]; p1.w = u[7];
    *(uint4*)dst = p0;
    *(uint4*)(dst + 8) = p1;

    psum[fl][cg] = part;
    __syncthreads();
    if (t < 64) {
        float s = psum[t][0] + psum[t][1] + psum[t][2] + psum[t][3];
        partS[((size_t)(b * NF + ft * 64 + t)) * 4 + ct] = s;
    }
}

// ---------------------------------------------------------------------------
// Kernel 3: init_scores = sigmoid(sum of 4 partials + b_mlp) -> d_out scores
// ---------------------------------------------------------------------------
__global__ void init_scores_kernel(const float* __restrict__ partS,
                                   const float* __restrict__ b_mlp,
                                   float* __restrict__ sc) {
    int i = blockIdx.x * 256 + threadIdx.x;   // over B*F
    float s = partS[i * 4] + partS[i * 4 + 1] + partS[i * 4 + 2] + partS[i * 4 + 3] + b_mlp[0];
    sc[i] = 1.f / (1.f + expf(-s));
}

// ---------------------------------------------------------------------------
// Kernel 4: gathered GEMM  h = [feat|feat[adj0..2]] @ W_conv + b_conv,
// InstanceNorm over C in-epilogue, store h_norm to d_out, pred = sigmoid(h@Wmlp).
// Block: 64 faces x 256 channels (full N), 256 threads = 4 waves (1x4 of 64x64).
// Per-block: 1 wave/SIMD, 41KB LDS, ~152 regs (no spill at lb(256,3))
// -> 3 blocks/CU co-resident; their barrier phases interleave per SIMD
// (the m97 mechanism). R2's lb(512,4) spilled ~60 regs -> 124MB scratch
// writes; this keeps the occupancy WITHOUT the spill.
// ---------------------------------------------------------------------------
__global__ __launch_bounds__(256, 3) void conv_gemm_kernel(
    const u16* __restrict__ featsT, const u16* __restrict__ Wt,
    const float* __restrict__ b_conv, const float* __restrict__ W_mlp,
    const float* __restrict__ b_mlp, const int* __restrict__ adj,
    float* __restrict__ out_feat, float* __restrict__ pred) {
    __shared__ __align__(16) u16 AB[64 * 64 + 256 * 64];  // A: 8KB, B: 32KB
    __shared__ int srcIdx[64 * 4];
    u16* Albs = AB;
    u16* Blbs = AB + 64 * 64;
    float* red = (float*)AB;          // epilogue alias
    float* mstd = (float*)AB + 1024;  // epilogue alias

    int bx = blockIdx.x;
    int b = bx >> 8;
    int f0 = (bx & 255) << 6;
    int tid = threadIdx.x;
    int w = tid >> 6, lane = tid & 63;
    const int wn = w;                 // wave covers cols wn*64..+63, all 64 rows
    const int c16 = lane & 15, q4 = lane >> 4;

    if (tid < 64) {
        int f = f0 + tid;
        const int* ap = adj + ((size_t)(b * NF + f)) * 3;
        srcIdx[tid * 4 + 0] = f;
        srcIdx[tid * 4 + 1] = ap[0];
        srcIdx[tid * 4 + 2] = ap[1];
        srcIdx[tid * 4 + 3] = ap[2];
    }
    f32x4 acc[4][4] = {};
    const size_t meshBase = (size_t)b * NF * 256;
    __syncthreads();

    for (int kk = 0; kk < 16; ++kk) {
        int slot = kk >> 2;            // 0=self, 1..3=adj
        int ch0 = (kk & 3) << 6;       // channel offset within slot
        // --- stage A (gathered rows, 64 rows x 64ch) via global_load_lds ---
        {
            int rrow = (w << 4) + (lane >> 3) + ((lane >> 3) >= 8 ? 0 : 0); // placeholder
        }
#pragma unroll
        for (int p = 0; p < 2; ++p) {
            int rrow = ((w * 2 + p) << 3) + (lane >> 3);   // 0..63
            int c8 = lane & 7;
            int src = srcIdx[rrow * 4 + slot];
            const u16* gp = featsT + meshBase + (size_t)src * 256 + ch0 + ((c8 ^ (rrow & 7)) << 3);
            __builtin_amdgcn_global_load_lds((const __attribute__((address_space(1))) void*)gp,
                                             (__attribute__((address_space(3))) void*)&Albs[(w * 2 + p) * 512],
                                             16, 0, 0);
        }
        // --- stage B (weights, 256 n x 64 k) ---
#pragma unroll
        for (int p = 0; p < 8; ++p) {
            int n = ((w * 8 + p) << 3) + (lane >> 3);      // 0..255
            int c8 = lane & 7;
            const u16* gp = Wt + n * 1024 + (kk << 6) + ((c8 ^ (n & 7)) << 3);
            __builtin_amdgcn_global_load_lds((const __attribute__((address_space(1))) void*)gp,
                                             (__attribute__((address_space(3))) void*)&Blbs[(w * 8 + p) * 512],
                                             16, 0, 0);
        }
        __syncthreads();
        // --- compute: 2 k-halves x 4x4 MFMAs (wave tile 64x64) ---
#pragma unroll
        for (int kh = 0; kh < 2; ++kh) {
            int k8 = (kh << 2) + q4;
            bf16x8 af[4], bfr[4];
#pragma unroll
            for (int mi = 0; mi < 4; ++mi) {
                int m = (mi << 4) + c16;                    // 0..63
                af[mi] = *(const bf16x8*)&Albs[(m << 6) + ((k8 ^ (m & 7)) << 3)];
            }
#pragma unroll
            for (int ni = 0; ni < 4; ++ni) {
                int n = (wn << 6) + (ni << 4) + c16;        // 0..255
                bfr[ni] = *(const bf16x8*)&Blbs[(n << 6) + ((k8 ^ (n & 7)) << 3)];
            }
#pragma unroll
            for (int mi = 0; mi < 4; ++mi)
#pragma unroll
                for (int ni = 0; ni < 4; ++ni)
                    acc[mi][ni] = __builtin_amdgcn_mfma_f32_16x16x32_bf16(af[mi], bfr[ni], acc[mi][ni], 0, 0, 0);
        }
        __syncthreads();
    }

    // ---------------- epilogue: bias + InstanceNorm + store + pred ----------
    float bcv[4], wml[4];
#pragma unroll
    for (int ni = 0; ni < 4; ++ni) {
        int col = (wn << 6) + (ni << 4) + c16;
        bcv[ni] = b_conv[col];
        wml[ni] = W_mlp[col];
    }
    float s[4][4], q2[4][4];
#pragma unroll
    for (int mi = 0; mi < 4; ++mi)
#pragma unroll
        for (int r = 0; r < 4; ++r) {
            float ss = 0.f, qq = 0.f;
#pragma unroll
            for (int ni = 0; ni < 4; ++ni) {
                float v = acc[mi][ni][r] + bcv[ni];
                acc[mi][ni][r] = v;
                ss += v; qq += v * v;
            }
            s[mi][r] = ss; q2[mi][r] = qq;
        }
#pragma unroll
    for (int msk = 1; msk < 16; msk <<= 1)
#pragma unroll
        for (int mi = 0; mi < 4; ++mi)
#pragma unroll
            for (int r = 0; r < 4; ++r) {
                s[mi][r] += __shfl_xor(s[mi][r], msk);
                q2[mi][r] += __shfl_xor(q2[mi][r], msk);
            }
    if (c16 == 0) {
#pragma unroll
        for (int mi = 0; mi < 4; ++mi)
#pragma unroll
            for (int r = 0; r < 4; ++r) {
                int row = (mi << 4) + (q4 << 2) + r;       // 0..63
                red[(row * 4 + wn) * 2 + 0] = s[mi][r];
                red[(row * 4 + wn) * 2 + 1] = q2[mi][r];
            }
    }
    __syncthreads();
    if (tid < 64) {
        float ss = red[tid * 8 + 0] + red[tid * 8 + 2] + red[tid * 8 + 4] + red[tid * 8 + 6];
        float qq = red[tid * 8 + 1] + red[tid * 8 + 3] + red[tid * 8 + 5] + red[tid * 8 + 7];
        float mean = ss * (1.f / 256.f);
        float var = qq * (1.f / 256.f) - mean * mean;
        mstd[tid * 2 + 0] = mean;
        mstd[tid * 2 + 1] = rsqrtf(var + 1e-5f);
    }
    __syncthreads();
    float ps[4][4];
#pragma unroll
    for (int mi = 0; mi < 4; ++mi)
#pragma unroll
        for (int r = 0; r < 4; ++r) {
            int row = (mi << 4) + (q4 << 2) + r;
            float mean = mstd[row * 2], rstd = mstd[row * 2 + 1];
            float* op = out_feat + meshBase + (size_t)(f0 + row) * 256 + (wn << 6) + c16;
            float pp = 0.f;
#pragma unroll
            for (int ni = 0; ni < 4; ++ni) {
                float hn = (acc[mi][ni][r] - mean) * rstd;
                op[ni << 4] = hn;
                pp += hn * wml[ni];
            }
            ps[mi][r] = pp;
        }
#pragma unroll
    for (int msk = 1; msk < 16; msk <<= 1)
#pragma unroll
        for (int mi = 0; mi < 4; ++mi)
#pragma unroll
            for (int r = 0; r < 4; ++r)
                ps[mi][r] += __shfl_xor(ps[mi][r], msk);
    __syncthreads();
    if (c16 == 0) {
#pragma unroll
        for (int mi = 0; mi < 4; ++mi)
#pragma unroll
            for (int r = 0; r < 4; ++r) {
                int row = (mi << 4) + (q4 << 2) + r;
                red[row * 4 + wn] = ps[mi][r];
            }
    }
    __syncthreads();
    if (tid < 64) {
        float t = red[tid * 4] + red[tid * 4 + 1] + red[tid * 4 + 2] + red[tid * 4 + 3] + b_mlp[0];
        pred[b * NF + f0 + tid] = 1.f / (1.f + expf(-t));
    }
}

// ---------------------------------------------------------------------------
// Kernel 5: BFS flood fill — dense bitmask version (R1; measured ~17us faster
// than the R2 queue version). One block per mesh, 20 synchronous levels.
// ---------------------------------------------------------------------------
__global__ __launch_bounds__(1024) void bfs_kernel(
    const int* __restrict__ adj, const int* __restrict__ anchors,
    const float* __restrict__ pred, float* __restrict__ sc,
    u32* __restrict__ doneOut) {
    __shared__ u32 done[512], bnd[512], nxt[512];
    int b = blockIdx.x, tid = threadIdx.x;
    if (tid < 512) { done[tid] = 0u; bnd[tid] = 0u; }
    __syncthreads();
    if (tid == 0) {
        int a = anchors[b];
        done[a >> 5] |= 1u << (a & 31);
        bnd[a >> 5] |= 1u << (a & 31);
    }
    const int* adjb = adj + (size_t)b * NF * 3;
    const float* pb = pred + b * NF;
    float* scb = sc + b * NF;
    __syncthreads();
    for (int step = 0; step < NSTEPS; ++step) {
        if (tid < 512) nxt[tid] = 0u;
        __syncthreads();
        for (int i = 0; i < 16; ++i) {
            int f = tid + (i << 10);
            if ((bnd[f >> 5] >> (f & 31)) & 1u) {
                int a0 = adjb[f * 3 + 0], a1 = adjb[f * 3 + 1], a2 = adjb[f * 3 + 2];
                bool d0 = (done[a0 >> 5] >> (a0 & 31)) & 1u;
                bool d1 = (done[a1 >> 5] >> (a1 & 31)) & 1u;
                bool d2 = (done[a2 >> 5] >> (a2 & 31)) & 1u;
                float nb = -1.f;
                if (d0) nb = fmaxf(nb, scb[a0]);
                if (d1) nb = fmaxf(nb, scb[a1]);
                if (d2) nb = fmaxf(nb, scb[a2]);
                if (!(d0 | d1 | d2)) nb = 1.f;
                float nv = fminf(fmaxf(pb[f], scb[f]), nb);
                scb[f] = nv;
                atomicOr(&nxt[a0 >> 5], 1u << (a0 & 31));
                atomicOr(&nxt[a1 >> 5], 1u << (a1 & 31));
                atomicOr(&nxt[a2 >> 5], 1u << (a2 & 31));
            }
        }
        __syncthreads();
        if (tid < 512) {
            u32 d2w = done[tid] | bnd[tid];
            done[tid] = d2w;
            bnd[tid] = nxt[tid] & ~d2w;
        }
        __syncthreads();
    }
    if (tid < 512) doneOut[b * 512 + tid] = done[tid];
}

// ---------------------------------------------------------------------------
// Kernel 6: faces never visited keep original (fp32) features.
// ---------------------------------------------------------------------------
__global__ void fixup_kernel(const float* __restrict__ x, const u32* __restrict__ doneBits,
                             float* __restrict__ out_feat) {
    int b = blockIdx.y;
    int f = (blockIdx.x << 8) + threadIdx.x;
    if (!((doneBits[b * 512 + (f >> 5)] >> (f & 31)) & 1u)) {
        float* op = out_feat + ((size_t)(b * NF + f)) * 256;
        const float* xp = x + (size_t)b * 256 * NF + f;
        for (int cc = 0; cc < 256; ++cc) op[cc] = xp[(size_t)cc * NF];
    }
}

// ---------------------------------------------------------------------------
extern "C" void kernel_launch(void* const* d_in, const int* in_sizes, int n_in,
                              void* d_out, int out_size, void* d_ws, size_t ws_size,
                              hipStream_t stream) {
    const float* x = (const float*)d_in[0];
    const int* adj = (const int*)d_in[1];
    const int* anchors = (const int*)d_in[2];
    const float* W_conv = (const float*)d_in[3];
    const float* b_conv = (const float*)d_in[4];
    const float* W_mlp = (const float*)d_in[5];
    const float* b_mlp = (const float*)d_in[6];

    float* out_feat = (float*)d_out;
    float* out_sc = out_feat + (size_t)NB * NF * 256;

    char* wsp = (char*)d_ws;
    u16* featsT = (u16*)wsp;  wsp += (size_t)NB * NF * 256 * 2;     // 67 MB
    u16* Wt = (u16*)wsp;      wsp += (size_t)256 * 1024 * 2;        // 512 KB
    float* partS = (float*)wsp; wsp += (size_t)NB * NF * 4 * 4;     // 2 MB
    float* pred = (float*)wsp;  wsp += (size_t)NB * NF * 4;         // 512 KB
    u32* doneBits = (u32*)wsp;  wsp += (size_t)NB * 512 * 4;        // 16 KB

    prep_w_kernel<<<1024, 256, 0, stream>>>(W_conv, Wt);
    transpose_kernel<<<dim3(256, 4, NB), 256, 0, stream>>>(x, featsT, W_mlp, partS);
    init_scores_kernel<<<512, 256, 0, stream>>>(partS, b_mlp, out_sc);
    conv_gemm_kernel<<<2048, 256, 0, stream>>>(featsT, Wt, b_conv, W_mlp, b_mlp, adj, out_feat, pred);
    bfs_kernel<<<NB, 1024, 0, stream>>>(adj, anchors, pred, out_sc, doneBits);
    fixup_kernel<<<dim3(64, NB), 256, 0, stream>>>(x, doneBits, out_feat);
}

// Round 4
// 411.606 us; speedup vs baseline: 1.0792x; 1.0057x over previous
//
#include <hip/hip_runtime.h>
#include <math.h>

// Problem constants (match reference setup_inputs)
#define NB 8
#define NC 256
#define NF 16384
#define NSTEPS 20

typedef unsigned short u16;
typedef unsigned int u32;
typedef __bf16 bf16x8 __attribute__((ext_vector_type(8)));
typedef float f32x4 __attribute__((ext_vector_type(4)));

__device__ __forceinline__ u16 f2bf(float f) {
    u32 u = __float_as_uint(f);
    u += 0x7fffu + ((u >> 16) & 1u);   // round-to-nearest-even
    return (u16)(u >> 16);
}
__device__ __forceinline__ float bf2f(u16 v) {
    return __uint_as_float(((u32)v) << 16);
}

// ---------------------------------------------------------------------------
// Kernel 1: W_conv [1024,256] fp32 -> Wt [256 n][1024 k] bf16 (transposed)
// ---------------------------------------------------------------------------
__global__ void prep_w_kernel(const float* __restrict__ Wc, u16* __restrict__ Wt) {
    int i = blockIdx.x * 256 + threadIdx.x;   // over 256*1024
    int n = i >> 10, k = i & 1023;
    Wt[i] = f2bf(Wc[k * 256 + n]);
}

// ---------------------------------------------------------------------------
// Kernel 2: transpose x [B,C,F] fp32 -> featsT [B,F,C] bf16, plus partial
// dot(feats, W_mlp) per face per 64-channel tile (for init_scores).
// ---------------------------------------------------------------------------
__global__ __launch_bounds__(256) void transpose_kernel(
    const float* __restrict__ x, u16* __restrict__ featsT,
    const float* __restrict__ W_mlp, float* __restrict__ partS) {
    __shared__ float tile[64][69];   // odd pad -> 2-way LDS banks on col reads (free)
    __shared__ float psum[64][4];
    int ft = blockIdx.x, ct = blockIdx.y, b = blockIdx.z;
    int t = threadIdx.x;
    int r = t >> 2, cg = t & 3;

    const float* xp = x + ((size_t)(b * 256 + ct * 64 + r)) * NF + ft * 64 + cg * 16;
    float4 v0 = *(const float4*)(xp + 0);
    float4 v1 = *(const float4*)(xp + 4);
    float4 v2 = *(const float4*)(xp + 8);
    float4 v3 = *(const float4*)(xp + 12);
    float* tr = &tile[r][cg * 16];
    tr[0] = v0.x; tr[1] = v0.y; tr[2]  = v0.z; tr[3]  = v0.w;
    tr[4] = v1.x; tr[5] = v1.y; tr[6]  = v1.z; tr[7]  = v1.w;
    tr[8] = v2.x; tr[9] = v2.y; tr[10] = v2.z; tr[11] = v2.w;
    tr[12] = v3.x; tr[13] = v3.y; tr[14] = v3.z; tr[15] = v3.w;
    __syncthreads();

    int fl = t >> 2;          // face local 0..63
    int c0 = cg * 16;         // channel sub-range
    float part = 0.f;
    u16 tmp[16];
#pragma unroll
    for (int j = 0; j < 16; ++j) {
        float v = tile[c0 + j][fl];
        part += v * W_mlp[ct * 64 + c0 + j];
        tmp[j] = f2bf(v);
    }
    u16* dst = featsT + ((size_t)(b * NF + ft * 64 + fl)) * 256 + ct * 64 + c0;
    u32 u[8];
#pragma unroll
    for (int j = 0; j < 8; ++j) u[j] = (u32)tmp[2 * j] | ((u32)tmp[2 * j + 1] << 16);
    uint4 p0; p0.x = u[0]; p0.y = u[1]; p0.z = u[2]; p0.w = u[3];
    uint4 p1; p1.x = u[4]; p1.y = u[5]; p1.z = u[6]; p1.w = u[7];
    *(uint4*)dst = p0;
    *(uint4*)(dst + 8) = p1;

    psum[fl][cg] = part;
    __syncthreads();
    if (t < 64) {
        float s = psum[t][0] + psum[t][1] + psum[t][2] + psum[t][3];
        partS[((size_t)(b * NF + ft * 64 + t)) * 4 + ct] = s;
    }
}

// ---------------------------------------------------------------------------
// Kernel 3: gathered GEMM  h = [feat|feat[adj0..2]] @ W_conv + b_conv,
// InstanceNorm over C in-epilogue, store h_norm to d_out, pred = sigmoid(h@Wmlp).
// Block: 64 faces x 256 channels (full N), 256 threads = 4 waves (1x4 of 64x64).
// 1 wave/SIMD, 41KB LDS, ~148 unified regs at lb(256,3) -> 3 blocks/CU,
// barrier phases interleave (m97 mechanism), no spill.
// ---------------------------------------------------------------------------
__global__ __launch_bounds__(256, 3) void conv_gemm_kernel(
    const u16* __restrict__ featsT, const u16* __restrict__ Wt,
    const float* __restrict__ b_conv, const float* __restrict__ W_mlp,
    const float* __restrict__ b_mlp, const int* __restrict__ adj,
    float* __restrict__ out_feat, float* __restrict__ pred) {
    __shared__ __align__(16) u16 AB[64 * 64 + 256 * 64];  // A: 8KB, B: 32KB
    __shared__ int srcIdx[64 * 4];
    u16* Albs = AB;
    u16* Blbs = AB + 64 * 64;
    float* red = (float*)AB;          // epilogue alias
    float* mstd = (float*)AB + 1024;  // epilogue alias

    int bx = blockIdx.x;
    int b = bx >> 8;
    int f0 = (bx & 255) << 6;
    int tid = threadIdx.x;
    int w = tid >> 6, lane = tid & 63;
    const int wn = w;                 // wave covers cols wn*64..+63, all 64 rows
    const int c16 = lane & 15, q4 = lane >> 4;

    if (tid < 64) {
        int f = f0 + tid;
        const int* ap = adj + ((size_t)(b * NF + f)) * 3;
        srcIdx[tid * 4 + 0] = f;
        srcIdx[tid * 4 + 1] = ap[0];
        srcIdx[tid * 4 + 2] = ap[1];
        srcIdx[tid * 4 + 3] = ap[2];
    }
    f32x4 acc[4][4] = {};
    const size_t meshBase = (size_t)b * NF * 256;
    __syncthreads();

    for (int kk = 0; kk < 16; ++kk) {
        int slot = kk >> 2;            // 0=self, 1..3=adj
        int ch0 = (kk & 3) << 6;       // channel offset within slot
        // --- stage A (gathered rows, 64 rows x 64ch) via global_load_lds ---
#pragma unroll
        for (int p = 0; p < 2; ++p) {
            int rrow = ((w * 2 + p) << 3) + (lane >> 3);   // 0..63
            int c8 = lane & 7;
            int src = srcIdx[rrow * 4 + slot];
            const u16* gp = featsT + meshBase + (size_t)src * 256 + ch0 + ((c8 ^ (rrow & 7)) << 3);
            __builtin_amdgcn_global_load_lds((const __attribute__((address_space(1))) void*)gp,
                                             (__attribute__((address_space(3))) void*)&Albs[(w * 2 + p) * 512],
                                             16, 0, 0);
        }
        // --- stage B (weights, 256 n x 64 k) ---
#pragma unroll
        for (int p = 0; p < 8; ++p) {
            int n = ((w * 8 + p) << 3) + (lane >> 3);      // 0..255
            int c8 = lane & 7;
            const u16* gp = Wt + n * 1024 + (kk << 6) + ((c8 ^ (n & 7)) << 3);
            __builtin_amdgcn_global_load_lds((const __attribute__((address_space(1))) void*)gp,
                                             (__attribute__((address_space(3))) void*)&Blbs[(w * 8 + p) * 512],
                                             16, 0, 0);
        }
        __syncthreads();
        // --- compute: 2 k-halves x 4x4 MFMAs (wave tile 64x64) ---
#pragma unroll
        for (int kh = 0; kh < 2; ++kh) {
            int k8 = (kh << 2) + q4;
            bf16x8 af[4], bfr[4];
#pragma unroll
            for (int mi = 0; mi < 4; ++mi) {
                int m = (mi << 4) + c16;                    // 0..63
                af[mi] = *(const bf16x8*)&Albs[(m << 6) + ((k8 ^ (m & 7)) << 3)];
            }
#pragma unroll
            for (int ni = 0; ni < 4; ++ni) {
                int n = (wn << 6) + (ni << 4) + c16;        // 0..255
                bfr[ni] = *(const bf16x8*)&Blbs[(n << 6) + ((k8 ^ (n & 7)) << 3)];
            }
#pragma unroll
            for (int mi = 0; mi < 4; ++mi)
#pragma unroll
                for (int ni = 0; ni < 4; ++ni)
                    acc[mi][ni] = __builtin_amdgcn_mfma_f32_16x16x32_bf16(af[mi], bfr[ni], acc[mi][ni], 0, 0, 0);
        }
        __syncthreads();
    }

    // ---------------- epilogue: bias + InstanceNorm + store + pred ----------
    float bcv[4], wml[4];
#pragma unroll
    for (int ni = 0; ni < 4; ++ni) {
        int col = (wn << 6) + (ni << 4) + c16;
        bcv[ni] = b_conv[col];
        wml[ni] = W_mlp[col];
    }
    float s[4][4], q2[4][4];
#pragma unroll
    for (int mi = 0; mi < 4; ++mi)
#pragma unroll
        for (int r = 0; r < 4; ++r) {
            float ss = 0.f, qq = 0.f;
#pragma unroll
            for (int ni = 0; ni < 4; ++ni) {
                float v = acc[mi][ni][r] + bcv[ni];
                acc[mi][ni][r] = v;
                ss += v; qq += v * v;
            }
            s[mi][r] = ss; q2[mi][r] = qq;
        }
#pragma unroll
    for (int msk = 1; msk < 16; msk <<= 1)
#pragma unroll
        for (int mi = 0; mi < 4; ++mi)
#pragma unroll
            for (int r = 0; r < 4; ++r) {
                s[mi][r] += __shfl_xor(s[mi][r], msk);
                q2[mi][r] += __shfl_xor(q2[mi][r], msk);
            }
    if (c16 == 0) {
#pragma unroll
        for (int mi = 0; mi < 4; ++mi)
#pragma unroll
            for (int r = 0; r < 4; ++r) {
                int row = (mi << 4) + (q4 << 2) + r;       // 0..63
                red[(row * 4 + wn) * 2 + 0] = s[mi][r];
                red[(row * 4 + wn) * 2 + 1] = q2[mi][r];
            }
    }
    __syncthreads();
    if (tid < 64) {
        float ss = red[tid * 8 + 0] + red[tid * 8 + 2] + red[tid * 8 + 4] + red[tid * 8 + 6];
        float qq = red[tid * 8 + 1] + red[tid * 8 + 3] + red[tid * 8 + 5] + red[tid * 8 + 7];
        float mean = ss * (1.f / 256.f);
        float var = qq * (1.f / 256.f) - mean * mean;
        mstd[tid * 2 + 0] = mean;
        mstd[tid * 2 + 1] = rsqrtf(var + 1e-5f);
    }
    __syncthreads();
    float ps[4][4];
#pragma unroll
    for (int mi = 0; mi < 4; ++mi)
#pragma unroll
        for (int r = 0; r < 4; ++r) {
            int row = (mi << 4) + (q4 << 2) + r;
            float mean = mstd[row * 2], rstd = mstd[row * 2 + 1];
            float* op = out_feat + meshBase + (size_t)(f0 + row) * 256 + (wn << 6) + c16;
            float pp = 0.f;
#pragma unroll
            for (int ni = 0; ni < 4; ++ni) {
                float hn = (acc[mi][ni][r] - mean) * rstd;
                op[ni << 4] = hn;
                pp += hn * wml[ni];
            }
            ps[mi][r] = pp;
        }
#pragma unroll
    for (int msk = 1; msk < 16; msk <<= 1)
#pragma unroll
        for (int mi = 0; mi < 4; ++mi)
#pragma unroll
            for (int r = 0; r < 4; ++r)
                ps[mi][r] += __shfl_xor(ps[mi][r], msk);
    __syncthreads();
    if (c16 == 0) {
#pragma unroll
        for (int mi = 0; mi < 4; ++mi)
#pragma unroll
            for (int r = 0; r < 4; ++r) {
                int row = (mi << 4) + (q4 << 2) + r;
                red[row * 4 + wn] = ps[mi][r];
            }
    }
    __syncthreads();
    if (tid < 64) {
        float t = red[tid * 4] + red[tid * 4 + 1] + red[tid * 4 + 2] + red[tid * 4 + 3] + b_mlp[0];
        pred[b * NF + f0 + tid] = 1.f / (1.f + expf(-t));
    }
}

// ---------------------------------------------------------------------------
// Kernel 4: BFS flood fill — LDS-resident scores (bf16, 32KB) + bitmasks.
// Also computes init_scores from partS in-prologue (replaces init kernel).
// Global traffic: 12B adj + 4B pred per face TOTAL (each face frontier once),
// coalesced partS read + score write-back. One block per mesh, 20 levels.
// ---------------------------------------------------------------------------
__global__ __launch_bounds__(1024) void bfs_kernel(
    const int* __restrict__ adj, const int* __restrict__ anchors,
    const float* __restrict__ partS, const float* __restrict__ b_mlp,
    const float* __restrict__ pred, float* __restrict__ sc,
    u32* __restrict__ doneOut) {
    __shared__ u16 scL[NF];                    // 32 KB bf16 scores
    __shared__ u32 done[512], bnd[512], nxt[512];
    int b = blockIdx.x, tid = threadIdx.x;
    float bm = b_mlp[0];
    const float4* pS = (const float4*)(partS + (size_t)b * NF * 4);
    for (int i = tid; i < NF; i += 1024) {
        float4 p = pS[i];
        float s = p.x + p.y + p.z + p.w + bm;
        scL[i] = f2bf(1.f / (1.f + expf(-s)));
    }
    if (tid < 512) { done[tid] = 0u; bnd[tid] = 0u; }
    __syncthreads();
    if (tid == 0) {
        int a = anchors[b];
        done[a >> 5] |= 1u << (a & 31);
        bnd[a >> 5] |= 1u << (a & 31);
    }
    const int* adjb = adj + (size_t)b * NF * 3;
    const float* pb = pred + b * NF;
    __syncthreads();
    for (int step = 0; step < NSTEPS; ++step) {
        if (tid < 512) nxt[tid] = 0u;
        __syncthreads();
        for (int i = 0; i < 16; ++i) {
            int f = tid + (i << 10);
            if ((bnd[f >> 5] >> (f & 31)) & 1u) {
                int a0 = adjb[f * 3 + 0], a1 = adjb[f * 3 + 1], a2 = adjb[f * 3 + 2];
                bool d0 = (done[a0 >> 5] >> (a0 & 31)) & 1u;
                bool d1 = (done[a1 >> 5] >> (a1 & 31)) & 1u;
                bool d2 = (done[a2 >> 5] >> (a2 & 31)) & 1u;
                float nb = -1.f;
                if (d0) nb = fmaxf(nb, bf2f(scL[a0]));
                if (d1) nb = fmaxf(nb, bf2f(scL[a1]));
                if (d2) nb = fmaxf(nb, bf2f(scL[a2]));
                if (!(d0 | d1 | d2)) nb = 1.f;
                float nv = fminf(fmaxf(pb[f], bf2f(scL[f])), nb);
                scL[f] = f2bf(nv);
                atomicOr(&nxt[a0 >> 5], 1u << (a0 & 31));
                atomicOr(&nxt[a1 >> 5], 1u << (a1 & 31));
                atomicOr(&nxt[a2 >> 5], 1u << (a2 & 31));
            }
        }
        __syncthreads();
        if (tid < 512) {
            u32 d2w = done[tid] | bnd[tid];
            done[tid] = d2w;
            bnd[tid] = nxt[tid] & ~d2w;
        }
        __syncthreads();
    }
    for (int i = tid; i < NF; i += 1024) sc[b * NF + i] = bf2f(scL[i]);
    if (tid < 512) doneOut[b * 512 + tid] = done[tid];
}

// ---------------------------------------------------------------------------
// Kernel 5: faces never visited keep original (fp32) features.
// ---------------------------------------------------------------------------
__global__ void fixup_kernel(const float* __restrict__ x, const u32* __restrict__ doneBits,
                             float* __restrict__ out_feat) {
    int b = blockIdx.y;
    int f = (blockIdx.x << 8) + threadIdx.x;
    if (!((doneBits[b * 512 + (f >> 5)] >> (f & 31)) & 1u)) {
        float* op = out_feat + ((size_t)(b * NF + f)) * 256;
        const float* xp = x + (size_t)b * 256 * NF + f;
        for (int cc = 0; cc < 256; ++cc) op[cc] = xp[(size_t)cc * NF];
    }
}

// ---------------------------------------------------------------------------
extern "C" void kernel_launch(void* const* d_in, const int* in_sizes, int n_in,
                              void* d_out, int out_size, void* d_ws, size_t ws_size,
                              hipStream_t stream) {
    const float* x = (const float*)d_in[0];
    const int* adj = (const int*)d_in[1];
    const int* anchors = (const int*)d_in[2];
    const float* W_conv = (const float*)d_in[3];
    const float* b_conv = (const float*)d_in[4];
    const float* W_mlp = (const float*)d_in[5];
    const float* b_mlp = (const float*)d_in[6];

    float* out_feat = (float*)d_out;
    float* out_sc = out_feat + (size_t)NB * NF * 256;

    char* wsp = (char*)d_ws;
    u16* featsT = (u16*)wsp;  wsp += (size_t)NB * NF * 256 * 2;     // 67 MB
    u16* Wt = (u16*)wsp;      wsp += (size_t)256 * 1024 * 2;        // 512 KB
    float* partS = (float*)wsp; wsp += (size_t)NB * NF * 4 * 4;     // 2 MB
    float* pred = (float*)wsp;  wsp += (size_t)NB * NF * 4;         // 512 KB
    u32* doneBits = (u32*)wsp;  wsp += (size_t)NB * 512 * 4;        // 16 KB

    prep_w_kernel<<<1024, 256, 0, stream>>>(W_conv, Wt);
    transpose_kernel<<<dim3(256, 4, NB), 256, 0, stream>>>(x, featsT, W_mlp, partS);
    conv_gemm_kernel<<<2048, 256, 0, stream>>>(featsT, Wt, b_conv, W_mlp, b_mlp, adj, out_feat, pred);
    bfs_kernel<<<NB, 1024, 0, stream>>>(adj, anchors, partS, b_mlp, pred, out_sc, doneBits);
    fixup_kernel<<<dim3(64, NB), 256, 0, stream>>>(x, doneBits, out_feat);
}